// Round 1
// baseline (2268.428 us; speedup 1.0000x reference)
//
#include <hip/hip_runtime.h>
#include <hip/hip_bf16.h>
#include <math.h>

// Problem: B=2, T=2048, D=2048, N=8 heads, K=1 kv-head (MQA), H=256, F=16384.
// All matmuls in bf16 MFMA (16x16x32), fp32 accumulate. Output fp32.

using bf16 = __hip_bfloat16;
typedef short bf16x8 __attribute__((ext_vector_type(8)));
typedef float f32x4 __attribute__((ext_vector_type(4)));

__device__ __forceinline__ void gld_lds16(const bf16* g, bf16* l) {
    __builtin_amdgcn_global_load_lds(
        (const __attribute__((address_space(1))) void*)g,
        (__attribute__((address_space(3))) void*)l, 16, 0, 0);
}

// ---------------------------------------------------------------------------
// Generic GEMM: C[m,n] = sum_k A[m,k] * Bt[n,k]   (both operands K-contiguous)
// 128x128 tile, BK=32, 256 threads (4 waves, each 64x64 = 4x4 MFMA tiles).
// global_load_lds staging with XOR chunk swizzle (2-way LDS conflicts only).
// epi: 0 = store bf16, 1 = store f32, 2 = store f32 + residual add from res.
// Batched: blockIdx.z -> (zb, zn) with independent strides for A/B/C.
// ---------------------------------------------------------------------------
__global__ __launch_bounds__(256, 2)
void gemm_bt(const bf16* __restrict__ A, const bf16* __restrict__ Bm,
             void* __restrict__ Cv, const float* __restrict__ res,
             int K, int lda, int ldb, int ldc,
             long sAb, long sAn, long sBb, long sBn, long sCb, long sCn,
             int nInner, int epi)
{
    __shared__ bf16 As[128 * 32];
    __shared__ bf16 Bs[128 * 32];

    const int zb = blockIdx.z / nInner;
    const int zn = blockIdx.z - zb * nInner;
    A  += (long)zb * sAb + (long)zn * sAn;
    Bm += (long)zb * sBb + (long)zn * sBn;
    const long coff = (long)zb * sCb + (long)zn * sCn;

    const int tid  = threadIdx.x;
    const int lane = tid & 63;
    const int wave = tid >> 6;
    const int wm = wave >> 1;   // wave row (0..1)
    const int wn = wave & 1;    // wave col (0..1)
    const int lr = lane & 15;
    const int lq = lane >> 4;

    const long m_blk = (long)blockIdx.y * 128;
    const long n_blk = (long)blockIdx.x * 128;

    f32x4 acc[4][4] = {};

    // staging: 512 16B-chunks per tile; wave w, iter i covers chunks
    // [i*256 + w*64, +64). LDS slot pos in row m holds k-group (pos ^ ((m>>1)&3)).
    const int c0 = wave * 64 + lane;
    const int c1 = c0 + 256;
    const int am0 = c0 >> 2, am1 = c1 >> 2;
    const int ak0 = ((c0 & 3) ^ ((am0 >> 1) & 3)) * 8;
    const int ak1 = ((c1 & 3) ^ ((am1 >> 1) & 3)) * 8;
    const long aoff0 = (m_blk + am0) * (long)lda + ak0;
    const long aoff1 = (m_blk + am1) * (long)lda + ak1;
    const long boff0 = (n_blk + am0) * (long)ldb + ak0;
    const long boff1 = (n_blk + am1) * (long)ldb + ak1;
    bf16* lA0 = &As[(wave * 64) * 8];
    bf16* lA1 = &As[(256 + wave * 64) * 8];
    bf16* lB0 = &Bs[(wave * 64) * 8];
    bf16* lB1 = &Bs[(256 + wave * 64) * 8];

    for (int k0 = 0; k0 < K; k0 += 32) {
        gld_lds16(A + aoff0 + k0, lA0);
        gld_lds16(A + aoff1 + k0, lA1);
        gld_lds16(Bm + boff0 + k0, lB0);
        gld_lds16(Bm + boff1 + k0, lB1);
        __syncthreads();

        bf16x8 af[4], bfr[4];
        #pragma unroll
        for (int t = 0; t < 4; ++t) {
            const int mr = wm * 64 + t * 16 + lr;
            af[t]  = *(const bf16x8*)&As[(mr * 4 + (lq ^ ((mr >> 1) & 3))) * 8];
            const int nr = wn * 64 + t * 16 + lr;
            bfr[t] = *(const bf16x8*)&Bs[(nr * 4 + (lq ^ ((nr >> 1) & 3))) * 8];
        }
        #pragma unroll
        for (int mt = 0; mt < 4; ++mt)
            #pragma unroll
            for (int nt = 0; nt < 4; ++nt)
                acc[mt][nt] = __builtin_amdgcn_mfma_f32_16x16x32_bf16(
                    af[mt], bfr[nt], acc[mt][nt], 0, 0, 0);
        __syncthreads();
    }

    // epilogue: C/D layout col = lane&15, row = (lane>>4)*4 + reg
    #pragma unroll
    for (int mt = 0; mt < 4; ++mt) {
        #pragma unroll
        for (int nt = 0; nt < 4; ++nt) {
            const long col = n_blk + wn * 64 + nt * 16 + lr;
            #pragma unroll
            for (int r = 0; r < 4; ++r) {
                const long row = m_blk + wm * 64 + mt * 16 + lq * 4 + r;
                const long idx = coff + row * (long)ldc + col;
                const float v = acc[mt][nt][r];
                if (epi == 0)      ((bf16*)Cv)[idx]  = __float2bfloat16(v);
                else if (epi == 1) ((float*)Cv)[idx] = v;
                else               ((float*)Cv)[idx] = v + res[row * (long)ldc + col];
            }
        }
    }
}

// ---------------------------------------------------------------------------
// fp32 -> bf16 transpose (LDS 32x32 tile).  in: (R,C) ld=ldin, out: (C,R) ld=ldout
// ---------------------------------------------------------------------------
__global__ __launch_bounds__(256)
void transpose_f2b(const float* __restrict__ in, bf16* __restrict__ out,
                   int ldin, int ldout, long inB, long outB)
{
    __shared__ float tile[32][33];
    in  += (long)blockIdx.z * inB;
    out += (long)blockIdx.z * outB;
    const int r0 = blockIdx.y * 32, c0 = blockIdx.x * 32;
    const int tx = threadIdx.x & 31, ty = threadIdx.x >> 5;
    #pragma unroll
    for (int i = 0; i < 32; i += 8)
        tile[ty + i][tx] = in[(long)(r0 + ty + i) * ldin + c0 + tx];
    __syncthreads();
    #pragma unroll
    for (int i = 0; i < 32; i += 8)
        out[(long)(c0 + ty + i) * ldout + r0 + tx] = __float2bfloat16(tile[tx][ty + i]);
}

// bf16 -> bf16 transpose (for V)
__global__ __launch_bounds__(256)
void transpose_b2b(const bf16* __restrict__ in, bf16* __restrict__ out,
                   int ldin, int ldout, long inB, long outB)
{
    __shared__ bf16 tile[32][33];
    in  += (long)blockIdx.z * inB;
    out += (long)blockIdx.z * outB;
    const int r0 = blockIdx.y * 32, c0 = blockIdx.x * 32;
    const int tx = threadIdx.x & 31, ty = threadIdx.x >> 5;
    #pragma unroll
    for (int i = 0; i < 32; i += 8)
        tile[ty + i][tx] = in[(long)(r0 + ty + i) * ldin + c0 + tx];
    __syncthreads();
    #pragma unroll
    for (int i = 0; i < 32; i += 8)
        out[(long)(c0 + ty + i) * ldout + r0 + tx] = tile[tx][ty + i];
}

// ---------------------------------------------------------------------------
// RMSNorm: row of 2048 fp32 -> bf16, out = x * rsqrt(mean(x^2)+1e-6) * (1+scale)
// ---------------------------------------------------------------------------
__global__ __launch_bounds__(256)
void rmsnorm_k(const float* __restrict__ x, const float* __restrict__ scale,
               bf16* __restrict__ out)
{
    const long row = blockIdx.x;
    const float* xr = x + row * 2048;
    const int tid = threadIdx.x;
    const float4 a = ((const float4*)xr)[tid];
    const float4 b = ((const float4*)xr)[tid + 256];
    float ss = a.x*a.x + a.y*a.y + a.z*a.z + a.w*a.w
             + b.x*b.x + b.y*b.y + b.z*b.z + b.w*b.w;
    for (int o = 32; o; o >>= 1) ss += __shfl_down(ss, o, 64);
    __shared__ float red[4];
    const int lane = tid & 63, wave = tid >> 6;
    if (lane == 0) red[wave] = ss;
    __syncthreads();
    const float inv = rsqrtf((red[0] + red[1] + red[2] + red[3]) * (1.f / 2048.f) + 1e-6f);
    const float4 s0 = ((const float4*)scale)[tid];
    const float4 s1 = ((const float4*)scale)[tid + 256];
    bf16* orow = out + row * 2048;
    const int i0 = tid * 4, i1 = 1024 + tid * 4;
    orow[i0 + 0] = __float2bfloat16(a.x * inv * (1.f + s0.x));
    orow[i0 + 1] = __float2bfloat16(a.y * inv * (1.f + s0.y));
    orow[i0 + 2] = __float2bfloat16(a.z * inv * (1.f + s0.z));
    orow[i0 + 3] = __float2bfloat16(a.w * inv * (1.f + s0.w));
    orow[i1 + 0] = __float2bfloat16(b.x * inv * (1.f + s1.x));
    orow[i1 + 1] = __float2bfloat16(b.y * inv * (1.f + s1.y));
    orow[i1 + 2] = __float2bfloat16(b.z * inv * (1.f + s1.z));
    orow[i1 + 3] = __float2bfloat16(b.w * inv * (1.f + s1.w));
}

// ---------------------------------------------------------------------------
// RoPE in-place on qkv rows (2560 wide): heads 0..7 = q (scaled by H^-0.5),
// head 8 = k. half = 128. v (cols 2304..2559) untouched.
// ---------------------------------------------------------------------------
__global__ __launch_bounds__(256)
void rope_k(bf16* __restrict__ qkv, const int* __restrict__ positions)
{
    const long row = blockIdx.x;
    const float pos = (float)positions[row];
    bf16* rp = qkv + row * 2560;
    for (int w = threadIdx.x; w < 1152; w += 256) {
        const int head = w >> 7;
        const int j = w & 127;
        const int base = head * 256;
        const float x1 = __bfloat162float(rp[base + j]);
        const float x2 = __bfloat162float(rp[base + 128 + j]);
        const float ts = powf(10000.f, (float)j * (1.f / 128.f));
        const float rad = pos / ts;
        const float s = sinf(rad), c = cosf(rad);
        const float sc = (head < 8) ? 0.0625f : 1.0f;  // H^-0.5 = 1/16 for q
        rp[base + j]       = __float2bfloat16((x1 * c - x2 * s) * sc);
        rp[base + 128 + j] = __float2bfloat16((x2 * c + x1 * s) * sc);
    }
}

// ---------------------------------------------------------------------------
// Causal softmax over one row (length 2048, valid s <= t). fp32 in, bf16 out.
// grid = (2048 t, 16 z), block = 256; row held in registers (8/thread).
// ---------------------------------------------------------------------------
__global__ __launch_bounds__(256)
void softmax_causal(const float* __restrict__ logits, bf16* __restrict__ probs)
{
    const int t = blockIdx.x;
    const long rowid = (long)blockIdx.y * 2048 + t;
    const float* lrow = logits + rowid * 2048;
    bf16* prow = probs + rowid * 2048;
    const int tid = threadIdx.x;
    const float4 a = ((const float4*)lrow)[tid];
    const float4 b = ((const float4*)lrow)[tid + 256];
    const int s0 = tid * 4, s1 = 1024 + tid * 4;
    float va[8] = {a.x, a.y, a.z, a.w, b.x, b.y, b.z, b.w};
    int   sidx[8] = {s0, s0+1, s0+2, s0+3, s1, s1+1, s1+2, s1+3};

    float mx = -3.0e38f;
    #pragma unroll
    for (int i = 0; i < 8; ++i) if (sidx[i] <= t) mx = fmaxf(mx, va[i]);
    for (int o = 32; o; o >>= 1) mx = fmaxf(mx, __shfl_down(mx, o, 64));
    __shared__ float red[4];
    const int lane = tid & 63, wave = tid >> 6;
    if (lane == 0) red[wave] = mx;
    __syncthreads();
    mx = fmaxf(fmaxf(red[0], red[1]), fmaxf(red[2], red[3]));
    __syncthreads();

    float e[8]; float sum = 0.f;
    #pragma unroll
    for (int i = 0; i < 8; ++i) {
        e[i] = (sidx[i] <= t) ? __expf(va[i] - mx) : 0.f;
        sum += e[i];
    }
    for (int o = 32; o; o >>= 1) sum += __shfl_down(sum, o, 64);
    if (lane == 0) red[wave] = sum;
    __syncthreads();
    sum = red[0] + red[1] + red[2] + red[3];
    const float inv = 1.f / sum;
    #pragma unroll
    for (int i = 0; i < 8; ++i) prow[sidx[i]] = __float2bfloat16(e[i] * inv);
}

// ---------------------------------------------------------------------------
// acts = gelu_tanh(g0) * g1; g layout: row t has [g0 (16384) | g1 (16384)]
// ---------------------------------------------------------------------------
__global__ __launch_bounds__(256)
void gelu_mul_k(const bf16* __restrict__ g, bf16* __restrict__ acts)
{
    const long v = (long)blockIdx.x * 256 + threadIdx.x;  // 4 elems each
    const long f4 = v * 4;
    const long t = f4 >> 14;
    const int  f = (int)(f4 & 16383);
    const bf16* g0 = g + t * 32768 + f;
    const bf16* g1 = g0 + 16384;
    bf16* o = acts + t * 16384 + f;
    #pragma unroll
    for (int i = 0; i < 4; ++i) {
        const float xg = __bfloat162float(g0[i]);
        const float xv = __bfloat162float(g1[i]);
        const float c = xg + 0.044715f * xg * xg * xg;
        const float ge = 0.5f * xg * (1.f + tanhf(0.7978845608f * c));
        o[i] = __float2bfloat16(ge * xv);
    }
}

// ---------------------------------------------------------------------------
static inline void launch_gemm(const bf16* A, const bf16* Bm, void* C,
                               const float* res, int M, int N, int K,
                               int lda, int ldb, int ldc,
                               long sAb, long sAn, long sBb, long sBn,
                               long sCb, long sCn, int nOuter, int nInner,
                               int epi, hipStream_t s)
{
    dim3 g(N / 128, M / 128, nOuter * nInner);
    gemm_bt<<<g, dim3(256), 0, s>>>(A, Bm, C, res, K, lda, ldb, ldc,
                                    sAb, sAn, sBb, sBn, sCb, sCn, nInner, epi);
}

extern "C" void kernel_launch(void* const* d_in, const int* in_sizes, int n_in,
                              void* d_out, int out_size, void* d_ws, size_t ws_size,
                              hipStream_t stream)
{
    const float* x          = (const float*)d_in[0];
    const int*   positions  = (const int*)d_in[1];
    // d_in[2] = attn_mask (tril causal) -- applied analytically
    const float* q_w        = (const float*)d_in[3];
    const float* kv_w       = (const float*)d_in[4];
    const float* attn_vec_w = (const float*)d_in[5];
    const float* gating_w   = (const float*)d_in[6];
    const float* linear_w   = (const float*)d_in[7];
    const float* pre_attn_s = (const float*)d_in[8];
    const float* pre_ffw_s  = (const float*)d_in[9];
    float* out = (float*)d_out;

    // workspace layout (~680 MB high-water, with reuse)
    char* p = (char*)d_ws;
    auto alloc = [&](size_t bytes) { char* r = p; p += (bytes + 255) & ~(size_t)255; return r; };
    bf16*  Wqkv   = (bf16*)alloc(2560UL * 2048 * 2);     // [r][d], r: 8 q-heads,K,V
    bf16*  Wo     = (bf16*)alloc(2048UL * 2048 * 2);     // [d][nh]
    bf16*  Wg     = (bf16*)alloc(32768UL * 2048 * 2);    // [f | F+f][d]
    bf16*  Wl     = (bf16*)alloc(2048UL * 16384 * 2);    // [d][f]
    bf16*  h      = (bf16*)alloc(4096UL * 2048 * 2);     // rmsnorm out (reused for h2)
    bf16*  qkv    = (bf16*)alloc(4096UL * 2560 * 2);
    bf16*  vt     = (bf16*)alloc(2UL * 256 * 2048 * 2);  // [b][h][s]
    float* xmid   = (float*)alloc(4096UL * 2048 * 4);
    bf16*  enc    = (bf16*)alloc(4096UL * 2048 * 2);
    float* logits = (float*)alloc(16UL * 2048 * 2048 * 4);
    bf16*  probs  = (bf16*)alloc(16UL * 2048 * 2048 * 2);
    bf16*  gbuf   = (bf16*)logits;   // reuse: logits dead after softmax
    bf16*  acts   = probs;           // reuse: probs dead after PV gemm
    if ((size_t)(p - (char*)d_ws) > ws_size) return;  // ws too small -> fail visibly

    // ---- weight prep: transpose + cast to bf16 (K-contiguous B^T layout) ----
    transpose_f2b<<<dim3(8, 64, 8), 256, 0, stream>>>(q_w, Wqkv, 256, 2048,
                                                      2048L * 256, 256L * 2048);
    transpose_f2b<<<dim3(8, 64, 2), 256, 0, stream>>>(kv_w, Wqkv + 2048L * 2048,
                                                      256, 2048, 2048L * 256, 256L * 2048);
    transpose_f2b<<<dim3(64, 64, 1), 256, 0, stream>>>(attn_vec_w, Wo, 2048, 2048, 0, 0);
    transpose_f2b<<<dim3(512, 64, 2), 256, 0, stream>>>(gating_w, Wg, 16384, 2048,
                                                        2048L * 16384, 16384L * 2048);
    transpose_f2b<<<dim3(64, 512, 1), 256, 0, stream>>>(linear_w, Wl, 2048, 16384, 0, 0);

    // ---- attention ----
    rmsnorm_k<<<4096, 256, 0, stream>>>(x, pre_attn_s, h);
    // qkv = h @ Wqkv^T : (4096 x 2560)
    launch_gemm(h, Wqkv, qkv, nullptr, 4096, 2560, 2048, 2048, 2048, 2560,
                0, 0, 0, 0, 0, 0, 1, 1, 0, stream);
    rope_k<<<4096, 256, 0, stream>>>(qkv, positions);
    // v^T per batch: (256 x 2048)
    transpose_b2b<<<dim3(8, 64, 2), 256, 0, stream>>>(qkv + 2304, vt, 2560, 2048,
                                                      2048L * 2560, 256L * 2048);
    // logits[b,n,t,s] = q . k   (z = b*8+n)
    launch_gemm(qkv, qkv + 2048, logits, nullptr, 2048, 2048, 256, 2560, 2560, 2048,
                2048L * 2560, 256, 2048L * 2560, 0,
                8L * 2048 * 2048, 2048L * 2048, 2, 8, 1, stream);
    softmax_causal<<<dim3(2048, 16), 256, 0, stream>>>(logits, probs);
    // enc[b,t,n*256+h] = probs @ v
    launch_gemm(probs, vt, enc, nullptr, 2048, 256, 2048, 2048, 2048, 2048,
                8L * 2048 * 2048, 2048L * 2048, 256L * 2048, 0,
                2048L * 2048, 256, 2, 8, 0, stream);
    // xmid = x + enc @ Wo^T
    launch_gemm(enc, Wo, xmid, x, 4096, 2048, 2048, 2048, 2048, 2048,
                0, 0, 0, 0, 0, 0, 1, 1, 2, stream);

    // ---- FFW ----
    rmsnorm_k<<<4096, 256, 0, stream>>>(xmid, pre_ffw_s, h);  // h reused as h2
    // gbuf = h2 @ Wg^T : (4096 x 32768)  [g0 | g1]
    launch_gemm(h, Wg, gbuf, nullptr, 4096, 32768, 2048, 2048, 2048, 32768,
                0, 0, 0, 0, 0, 0, 1, 1, 0, stream);
    gelu_mul_k<<<65536, 256, 0, stream>>>(gbuf, acts);
    // out = xmid + acts @ Wl^T
    launch_gemm(acts, Wl, out, xmid, 4096, 2048, 16384, 16384, 16384, 2048,
                0, 0, 0, 0, 0, 0, 1, 1, 2, stream);
}

// Round 2
// 2112.922 us; speedup vs baseline: 1.0736x; 1.0736x over previous
//
#include <hip/hip_runtime.h>
#include <hip/hip_bf16.h>
#include <math.h>

// B=2, T=2048, D=2048, N=8 heads, K=1 kv-head (MQA), H=256, F=16384.
// All matmuls bf16 MFMA 16x16x32, fp32 accumulate. Output fp32.

using bf16 = __hip_bfloat16;
typedef short bf16x8 __attribute__((ext_vector_type(8)));
typedef float f32x4 __attribute__((ext_vector_type(4)));

__device__ __forceinline__ void gld_lds16(const bf16* g, bf16* l) {
    __builtin_amdgcn_global_load_lds(
        (const __attribute__((address_space(1))) void*)g,
        (__attribute__((address_space(3))) void*)l, 16, 0, 0);
}

// ---------------------------------------------------------------------------
// Generic GEMM: C[m,n] = sum_k A[m,k] * Bt[n,k]  (both K-contiguous)
// 128x128 tile, BK=32, 256 threads (4 waves, 4x4 MFMA frags each).
// Grouped swizzle (GROUP_M=8) for L2 B-panel reuse.
// epi: 0 = bf16 store, 1 = f32, 2 = f32 + residual, 3 = fused gelu-gate
// (interleaved g0/g1 columns, writes bf16 acts at col/2, ldc = F).
// ---------------------------------------------------------------------------
__global__ __launch_bounds__(256, 2)
void gemm_bt(const bf16* __restrict__ A, const bf16* __restrict__ Bm,
             void* __restrict__ Cv, const float* __restrict__ res,
             int K, int lda, int ldb, int ldc,
             long sAb, long sAn, long sBb, long sBn, long sCb, long sCn,
             int nInner, int epi)
{
    __shared__ bf16 As[128 * 32];
    __shared__ bf16 Bs[128 * 32];

    const int zb = blockIdx.z / nInner;
    const int zn = blockIdx.z - zb * nInner;
    A  += (long)zb * sAb + (long)zn * sAn;
    Bm += (long)zb * sBb + (long)zn * sBn;
    const long coff = (long)zb * sCb + (long)zn * sCn;

    // grouped swizzle: consecutive blocks walk M within a GROUP_M-row band
    const int GROUP = 8;
    const int num_n = gridDim.x, num_m = gridDim.y;
    const int pid = blockIdx.y * num_n + blockIdx.x;
    const int band = GROUP * num_n;
    const int group_id = pid / band;
    const int first_m = group_id * GROUP;
    const int gsz = min(num_m - first_m, GROUP);
    const int in_group = pid - group_id * band;
    const int pid_m = first_m + (in_group % gsz);
    const int pid_n = in_group / gsz;

    const int tid  = threadIdx.x;
    const int lane = tid & 63;
    const int wave = tid >> 6;
    const int wm = wave >> 1;
    const int wn = wave & 1;
    const int lr = lane & 15;
    const int lq = lane >> 4;

    const long m_blk = (long)pid_m * 128;
    const long n_blk = (long)pid_n * 128;

    f32x4 acc[4][4] = {};

    const int c0 = wave * 64 + lane;
    const int c1 = c0 + 256;
    const int am0 = c0 >> 2, am1 = c1 >> 2;
    const int ak0 = ((c0 & 3) ^ ((am0 >> 1) & 3)) * 8;
    const int ak1 = ((c1 & 3) ^ ((am1 >> 1) & 3)) * 8;
    const long aoff0 = (m_blk + am0) * (long)lda + ak0;
    const long aoff1 = (m_blk + am1) * (long)lda + ak1;
    const long boff0 = (n_blk + am0) * (long)ldb + ak0;
    const long boff1 = (n_blk + am1) * (long)ldb + ak1;
    bf16* lA0 = &As[(wave * 64) * 8];
    bf16* lA1 = &As[(256 + wave * 64) * 8];
    bf16* lB0 = &Bs[(wave * 64) * 8];
    bf16* lB1 = &Bs[(256 + wave * 64) * 8];

    for (int k0 = 0; k0 < K; k0 += 32) {
        gld_lds16(A + aoff0 + k0, lA0);
        gld_lds16(A + aoff1 + k0, lA1);
        gld_lds16(Bm + boff0 + k0, lB0);
        gld_lds16(Bm + boff1 + k0, lB1);
        __syncthreads();

        bf16x8 af[4], bfr[4];
        #pragma unroll
        for (int t = 0; t < 4; ++t) {
            const int mr = wm * 64 + t * 16 + lr;
            af[t]  = *(const bf16x8*)&As[(mr * 4 + (lq ^ ((mr >> 1) & 3))) * 8];
            const int nr = wn * 64 + t * 16 + lr;
            bfr[t] = *(const bf16x8*)&Bs[(nr * 4 + (lq ^ ((nr >> 1) & 3))) * 8];
        }
        #pragma unroll
        for (int mt = 0; mt < 4; ++mt)
            #pragma unroll
            for (int nt = 0; nt < 4; ++nt)
                acc[mt][nt] = __builtin_amdgcn_mfma_f32_16x16x32_bf16(
                    af[mt], bfr[nt], acc[mt][nt], 0, 0, 0);
        __syncthreads();
    }

    // epilogue: C/D layout col = lane&15, row = (lane>>4)*4 + reg
    #pragma unroll
    for (int mt = 0; mt < 4; ++mt) {
        #pragma unroll
        for (int nt = 0; nt < 4; ++nt) {
            const long col = n_blk + wn * 64 + nt * 16 + lr;
            #pragma unroll
            for (int r = 0; r < 4; ++r) {
                const long row = m_blk + wm * 64 + mt * 16 + lq * 4 + r;
                const float v = acc[mt][nt][r];
                if (epi == 0) {
                    ((bf16*)Cv)[coff + row * (long)ldc + col] = __float2bfloat16(v);
                } else if (epi == 1) {
                    ((float*)Cv)[coff + row * (long)ldc + col] = v;
                } else if (epi == 2) {
                    ((float*)Cv)[coff + row * (long)ldc + col] =
                        v + res[row * (long)ldc + col];
                } else {
                    // fused gelu-gate: even col = g0, odd col = g1 (same f)
                    const float pv = __shfl_xor(v, 1, 64);
                    const float g0 = (lr & 1) ? pv : v;
                    const float g1 = (lr & 1) ? v : pv;
                    const float u = g0 + 0.044715f * g0 * g0 * g0;
                    const float act = g0 / (1.f + __expf(-1.5957691216f * u)) * g1;
                    if (!(lr & 1))
                        ((bf16*)Cv)[row * (long)ldc + (col >> 1)] =
                            __float2bfloat16(act);
                }
            }
        }
    }
}

// ---------------------------------------------------------------------------
// fp32 -> bf16 transpose. in: (R,C) ld=ldin; out row = c*rowMul, ld=ldout.
// ---------------------------------------------------------------------------
__global__ __launch_bounds__(256)
void transpose_f2b(const float* __restrict__ in, bf16* __restrict__ out,
                   int ldin, int ldout, long inB, long outB, int rowMul)
{
    __shared__ float tile[32][33];
    in  += (long)blockIdx.z * inB;
    out += (long)blockIdx.z * outB;
    const int r0 = blockIdx.y * 32, c0 = blockIdx.x * 32;
    const int tx = threadIdx.x & 31, ty = threadIdx.x >> 5;
    #pragma unroll
    for (int i = 0; i < 32; i += 8)
        tile[ty + i][tx] = in[(long)(r0 + ty + i) * ldin + c0 + tx];
    __syncthreads();
    #pragma unroll
    for (int i = 0; i < 32; i += 8)
        out[(long)(c0 + ty + i) * rowMul * ldout + r0 + tx] =
            __float2bfloat16(tile[tx][ty + i]);
}

// bf16 -> bf16 transpose (for V)
__global__ __launch_bounds__(256)
void transpose_b2b(const bf16* __restrict__ in, bf16* __restrict__ out,
                   int ldin, int ldout, long inB, long outB)
{
    __shared__ bf16 tile[32][33];
    in  += (long)blockIdx.z * inB;
    out += (long)blockIdx.z * outB;
    const int r0 = blockIdx.y * 32, c0 = blockIdx.x * 32;
    const int tx = threadIdx.x & 31, ty = threadIdx.x >> 5;
    #pragma unroll
    for (int i = 0; i < 32; i += 8)
        tile[ty + i][tx] = in[(long)(r0 + ty + i) * ldin + c0 + tx];
    __syncthreads();
    #pragma unroll
    for (int i = 0; i < 32; i += 8)
        out[(long)(c0 + ty + i) * ldout + r0 + tx] = tile[tx][ty + i];
}

// ---------------------------------------------------------------------------
__global__ __launch_bounds__(256)
void rmsnorm_k(const float* __restrict__ x, const float* __restrict__ scale,
               bf16* __restrict__ out)
{
    const long row = blockIdx.x;
    const float* xr = x + row * 2048;
    const int tid = threadIdx.x;
    const float4 a = ((const float4*)xr)[tid];
    const float4 b = ((const float4*)xr)[tid + 256];
    float ss = a.x*a.x + a.y*a.y + a.z*a.z + a.w*a.w
             + b.x*b.x + b.y*b.y + b.z*b.z + b.w*b.w;
    for (int o = 32; o; o >>= 1) ss += __shfl_down(ss, o, 64);
    __shared__ float red[4];
    const int lane = tid & 63, wave = tid >> 6;
    if (lane == 0) red[wave] = ss;
    __syncthreads();
    const float inv = rsqrtf((red[0] + red[1] + red[2] + red[3]) * (1.f / 2048.f) + 1e-6f);
    const float4 s0 = ((const float4*)scale)[tid];
    const float4 s1 = ((const float4*)scale)[tid + 256];
    bf16* orow = out + row * 2048;
    const int i0 = tid * 4, i1 = 1024 + tid * 4;
    orow[i0 + 0] = __float2bfloat16(a.x * inv * (1.f + s0.x));
    orow[i0 + 1] = __float2bfloat16(a.y * inv * (1.f + s0.y));
    orow[i0 + 2] = __float2bfloat16(a.z * inv * (1.f + s0.z));
    orow[i0 + 3] = __float2bfloat16(a.w * inv * (1.f + s0.w));
    orow[i1 + 0] = __float2bfloat16(b.x * inv * (1.f + s1.x));
    orow[i1 + 1] = __float2bfloat16(b.y * inv * (1.f + s1.y));
    orow[i1 + 2] = __float2bfloat16(b.z * inv * (1.f + s1.z));
    orow[i1 + 3] = __float2bfloat16(b.w * inv * (1.f + s1.w));
}

// ---------------------------------------------------------------------------
// RoPE in-place on qkv rows (2560 wide): heads 0..7 = q (scaled by H^-0.5),
// head 8 = k. half = 128.
// ---------------------------------------------------------------------------
__global__ __launch_bounds__(256)
void rope_k(bf16* __restrict__ qkv, const int* __restrict__ positions)
{
    const long row = blockIdx.x;
    const float pos = (float)positions[row];
    bf16* rp = qkv + row * 2560;
    for (int w = threadIdx.x; w < 1152; w += 256) {
        const int head = w >> 7;
        const int j = w & 127;
        const int base = head * 256;
        const float x1 = __bfloat162float(rp[base + j]);
        const float x2 = __bfloat162float(rp[base + 128 + j]);
        const float ts = powf(10000.f, (float)j * (1.f / 128.f));
        const float rad = pos / ts;
        const float s = sinf(rad), c = cosf(rad);
        const float sc = (head < 8) ? 0.0625f : 1.0f;
        rp[base + j]       = __float2bfloat16((x1 * c - x2 * s) * sc);
        rp[base + 128 + j] = __float2bfloat16((x2 * c + x1 * s) * sc);
    }
}

// ---------------------------------------------------------------------------
// Causal softmax, bf16 in / bf16 out, row length 2048, valid s <= t.
// ---------------------------------------------------------------------------
__global__ __launch_bounds__(256)
void softmax_causal(const bf16* __restrict__ logits, bf16* __restrict__ probs)
{
    const int t = blockIdx.x;
    const long rowid = (long)blockIdx.y * 2048 + t;
    const bf16* lrow = logits + rowid * 2048;
    bf16* prow = probs + rowid * 2048;
    const int tid = threadIdx.x;
    const bf16x8 raw = *(const bf16x8*)(lrow + tid * 8);
    float va[8];
    #pragma unroll
    for (int i = 0; i < 8; ++i)
        va[i] = __uint_as_float(((unsigned)(unsigned short)raw[i]) << 16);
    const int s0 = tid * 8;

    float mx = -3.0e38f;
    #pragma unroll
    for (int i = 0; i < 8; ++i) if (s0 + i <= t) mx = fmaxf(mx, va[i]);
    for (int o = 32; o; o >>= 1) mx = fmaxf(mx, __shfl_down(mx, o, 64));
    __shared__ float red[4];
    const int lane = tid & 63, wave = tid >> 6;
    if (lane == 0) red[wave] = mx;
    __syncthreads();
    mx = fmaxf(fmaxf(red[0], red[1]), fmaxf(red[2], red[3]));
    __syncthreads();

    float e[8]; float sum = 0.f;
    #pragma unroll
    for (int i = 0; i < 8; ++i) {
        e[i] = (s0 + i <= t) ? __expf(va[i] - mx) : 0.f;
        sum += e[i];
    }
    for (int o = 32; o; o >>= 1) sum += __shfl_down(sum, o, 64);
    if (lane == 0) red[wave] = sum;
    __syncthreads();
    sum = red[0] + red[1] + red[2] + red[3];
    const float inv = 1.f / sum;
    #pragma unroll
    for (int i = 0; i < 8; ++i) prow[s0 + i] = __float2bfloat16(e[i] * inv);
}

// ---------------------------------------------------------------------------
static inline void launch_gemm(const bf16* A, const bf16* Bm, void* C,
                               const float* res, int M, int N, int K,
                               int lda, int ldb, int ldc,
                               long sAb, long sAn, long sBb, long sBn,
                               long sCb, long sCn, int nOuter, int nInner,
                               int epi, hipStream_t s)
{
    dim3 g(N / 128, M / 128, nOuter * nInner);
    gemm_bt<<<g, dim3(256), 0, s>>>(A, Bm, C, res, K, lda, ldb, ldc,
                                    sAb, sAn, sBb, sBn, sCb, sCn, nInner, epi);
}

extern "C" void kernel_launch(void* const* d_in, const int* in_sizes, int n_in,
                              void* d_out, int out_size, void* d_ws, size_t ws_size,
                              hipStream_t stream)
{
    const float* x          = (const float*)d_in[0];
    const int*   positions  = (const int*)d_in[1];
    const float* q_w        = (const float*)d_in[3];
    const float* kv_w       = (const float*)d_in[4];
    const float* attn_vec_w = (const float*)d_in[5];
    const float* gating_w   = (const float*)d_in[6];
    const float* linear_w   = (const float*)d_in[7];
    const float* pre_attn_s = (const float*)d_in[8];
    const float* pre_ffw_s  = (const float*)d_in[9];
    float* out = (float*)d_out;

    char* p = (char*)d_ws;
    auto alloc = [&](size_t bytes) { char* r = p; p += (bytes + 255) & ~(size_t)255; return r; };
    bf16*  Wqkv   = (bf16*)alloc(2560UL * 2048 * 2);     // [r][d]
    bf16*  Wo     = (bf16*)alloc(2048UL * 2048 * 2);     // [d][nh]
    bf16*  Wg     = (bf16*)alloc(32768UL * 2048 * 2);    // interleaved [2f+c][d]
    bf16*  Wl     = (bf16*)alloc(2048UL * 16384 * 2);    // [d][f]
    bf16*  h      = (bf16*)alloc(4096UL * 2048 * 2);
    bf16*  qkv    = (bf16*)alloc(4096UL * 2560 * 2);
    bf16*  vt     = (bf16*)alloc(2UL * 256 * 2048 * 2);
    float* xmid   = (float*)alloc(4096UL * 2048 * 4);
    bf16*  enc    = (bf16*)alloc(4096UL * 2048 * 2);
    bf16*  logits = (bf16*)alloc(16UL * 2048 * 2048 * 2);
    bf16*  probs  = (bf16*)alloc(16UL * 2048 * 2048 * 2);
    bf16*  acts   = logits;  // reuse: logits dead after softmax
    if ((size_t)(p - (char*)d_ws) > ws_size) return;

    // ---- weight prep ----
    transpose_f2b<<<dim3(8, 64, 8), 256, 0, stream>>>(q_w, Wqkv, 256, 2048,
                                                      2048L * 256, 256L * 2048, 1);
    transpose_f2b<<<dim3(8, 64, 2), 256, 0, stream>>>(kv_w, Wqkv + 2048L * 2048,
                                                      256, 2048, 2048L * 256, 256L * 2048, 1);
    transpose_f2b<<<dim3(64, 64, 1), 256, 0, stream>>>(attn_vec_w, Wo, 2048, 2048, 0, 0, 1);
    // gating: interleave g0/g1 -> row 2f+c  (outB = one row, rowMul = 2)
    transpose_f2b<<<dim3(512, 64, 2), 256, 0, stream>>>(gating_w, Wg, 16384, 2048,
                                                        2048L * 16384, 2048, 2);
    transpose_f2b<<<dim3(64, 512, 1), 256, 0, stream>>>(linear_w, Wl, 2048, 16384, 0, 0, 1);

    // ---- attention ----
    rmsnorm_k<<<4096, 256, 0, stream>>>(x, pre_attn_s, h);
    launch_gemm(h, Wqkv, qkv, nullptr, 4096, 2560, 2048, 2048, 2048, 2560,
                0, 0, 0, 0, 0, 0, 1, 1, 0, stream);
    rope_k<<<4096, 256, 0, stream>>>(qkv, positions);
    transpose_b2b<<<dim3(8, 64, 2), 256, 0, stream>>>(qkv + 2304, vt, 2560, 2048,
                                                      2048L * 2560, 256L * 2048);
    // logits[b,n,t,s] = q.k  (bf16 out)
    launch_gemm(qkv, qkv + 2048, logits, nullptr, 2048, 2048, 256, 2560, 2560, 2048,
                2048L * 2560, 256, 2048L * 2560, 0,
                8L * 2048 * 2048, 2048L * 2048, 2, 8, 0, stream);
    softmax_causal<<<dim3(2048, 16), 256, 0, stream>>>(logits, probs);
    launch_gemm(probs, vt, enc, nullptr, 2048, 256, 2048, 2048, 2048, 2048,
                8L * 2048 * 2048, 2048L * 2048, 256L * 2048, 0,
                2048L * 2048, 256, 2, 8, 0, stream);
    launch_gemm(enc, Wo, xmid, x, 4096, 2048, 2048, 2048, 2048, 2048,
                0, 0, 0, 0, 0, 0, 1, 1, 2, stream);

    // ---- FFW ----
    rmsnorm_k<<<4096, 256, 0, stream>>>(xmid, pre_ffw_s, h);
    // fused gating + gelu-gate: writes acts (4096 x 16384 bf16) directly
    launch_gemm(h, Wg, acts, nullptr, 4096, 32768, 2048, 2048, 2048, 16384,
                0, 0, 0, 0, 0, 0, 1, 1, 3, stream);
    launch_gemm(acts, Wl, out, xmid, 4096, 2048, 16384, 16384, 16384, 2048,
                0, 0, 0, 0, 0, 0, 1, 1, 2, stream);
}